// Round 18
// baseline (189.142 us; speedup 1.0000x reference)
//
#include <hip/hip_runtime.h>
#include <math.h>

// Problem constants (B=2,H=12,Q=2048,K=2048,D=128,NPOS=512)
#define DD    128
#define NPOS  512
#define KK    2048
#define RPB   16        // rows per block = MFMA M dimension
#define BLK   1024      // 16 waves: one wave per row in phase 2

typedef __attribute__((ext_vector_type(8))) short short8_t;  // 8 bf16
typedef __attribute__((ext_vector_type(4))) float f32x4;

union BfPack {
    unsigned u[4];
    short8_t v;
};

__device__ __forceinline__ float sigmoidf_fast(float x) {
    return __builtin_amdgcn_rcpf(1.0f + __expf(-x));
}

__device__ __forceinline__ unsigned pack_bf16(float lo, float hi) {
    return (__float_as_uint(hi) & 0xffff0000u) | (__float_as_uint(lo) >> 16);
}

__global__ __launch_bounds__(BLK, 8)
void cope_kernel(const float* __restrict__ query,     // [R, D]
                 const float* __restrict__ attn,      // [R, K]
                 const float* __restrict__ pos_emb,   // [D, NPOS]
                 const int*   __restrict__ npos_max_p,
                 float* __restrict__ out)              // [R, K]
{
    const int t    = threadIdx.x;
    const int wv   = t >> 6;       // wave id 0..15
    const int lane = t & 63;

    __shared__ float s_tab[RPB][NPOS + 1];   // +1 sentinel col

    const size_t row_base = (size_t)blockIdx.x * RPB;

    // ---------------- Phase 1: table GEMM via bf16 MFMA (R14 verbatim) -----
    {
        const int m  = lane & 15;
        const int g  = lane >> 4;
        const int n0 = wv * 32 + m;

        f32x4 acc0 = {0.f, 0.f, 0.f, 0.f};
        f32x4 acc1 = {0.f, 0.f, 0.f, 0.f};

        #pragma unroll
        for (int kk = 0; kk < 4; ++kk) {
            const int k0 = kk * 32 + g * 8;

            const float* qp = query + (row_base + m) * DD + k0;
            f32x4 a0 = *reinterpret_cast<const f32x4*>(qp);
            f32x4 a1 = *reinterpret_cast<const f32x4*>(qp + 4);
            BfPack af;
            af.u[0] = pack_bf16(a0.x, a0.y);
            af.u[1] = pack_bf16(a0.z, a0.w);
            af.u[2] = pack_bf16(a1.x, a1.y);
            af.u[3] = pack_bf16(a1.z, a1.w);

            const float* bp = pos_emb + (size_t)k0 * NPOS + n0;
            float b0[8], b1[8];
            #pragma unroll
            for (int j = 0; j < 8; ++j) {
                b0[j] = bp[(size_t)j * NPOS];
                b1[j] = bp[(size_t)j * NPOS + 16];
            }
            BfPack bf0, bf1;
            #pragma unroll
            for (int j = 0; j < 4; ++j) {
                bf0.u[j] = pack_bf16(b0[2 * j], b0[2 * j + 1]);
                bf1.u[j] = pack_bf16(b1[2 * j], b1[2 * j + 1]);
            }

            acc0 = __builtin_amdgcn_mfma_f32_16x16x32_bf16(af.v, bf0.v, acc0, 0, 0, 0);
            acc1 = __builtin_amdgcn_mfma_f32_16x16x32_bf16(af.v, bf1.v, acc1, 0, 0, 0);
        }

        #pragma unroll
        for (int r = 0; r < 4; ++r) {
            s_tab[g * 4 + r][n0]      = acc0[r];
            s_tab[g * 4 + r][n0 + 16] = acc1[r];
        }
        if (t < RPB) s_tab[t][NPOS] = 0.0f;   // sentinel
    }
    __syncthreads();

    // ---------------- Phase 1.5: repack table to bf16 pairs (R14 verbatim) -
    {
        float lo[8], hi[8];
        #pragma unroll
        for (int j = 0; j < 8; ++j) {
            const int e = lane + j * 64;
            lo[j] = s_tab[wv][e];
            hi[j] = s_tab[wv][e + 1];    // e=511 reads the sentinel
        }
        __syncthreads();
        unsigned* urow = reinterpret_cast<unsigned*>(s_tab[wv]);
        #pragma unroll
        for (int j = 0; j < 8; ++j)
            urow[lane + j * 64] = pack_bf16(lo[j], hi[j]);
    }
    __syncthreads();

    // ---------------- Phase 2: per-wave suffix scan + packed gather --------
    const size_t row = row_base + wv;
    const float* arow = attn + row * (size_t)KK;
    float*       orow = out  + row * (size_t)KK;
    const unsigned* utab = reinterpret_cast<const unsigned*>(s_tab[wv]);

    const float clampv = (float)(*npos_max_p - 1);

    float suff[8][4];   // within-lane suffix sums (inclusive)
    float lct[8];       // lane-chunk totals
    float incl[8];      // wave-suffix-inclusive scan of lane totals

    #pragma unroll
    for (int c = 0; c < 8; ++c) {
        f32x4 gv = *reinterpret_cast<const f32x4*>(arow + c * 256 + lane * 4);
        float s0 = sigmoidf_fast(gv.x);
        float s1 = sigmoidf_fast(gv.y);
        float s2 = sigmoidf_fast(gv.z);
        float s3 = sigmoidf_fast(gv.w);
        suff[c][3] = s3;
        suff[c][2] = s2 + suff[c][3];
        suff[c][1] = s1 + suff[c][2];
        suff[c][0] = s0 + suff[c][1];
        lct[c] = suff[c][0];

        // wave-level inclusive suffix scan (64 lanes) — R8/R14 verbatim
        float v = lct[c];
        #pragma unroll
        for (int off = 1; off < 64; off <<= 1) {
            float u = __shfl_down(v, off);
            if (lane + off < 64) v += u;
        }
        incl[c] = v;
    }

    float Tc[8];
    #pragma unroll
    for (int c = 0; c < 8; ++c) Tc[c] = __shfl(incl[c], 0);
    float offc[8];
    offc[7] = 0.0f;
    #pragma unroll
    for (int c = 6; c >= 0; --c) offc[c] = offc[c + 1] + Tc[c + 1];

    #pragma unroll
    for (int c = 0; c < 8; ++c) {
        float base = offc[c] + (incl[c] - lct[c]);
        f32x4 res;
        #pragma unroll
        for (int j = 0; j < 4; ++j) {
            float pos = fminf(suff[c][j] + base, clampv);
            int   ifl = (int)pos;          // pos >= 0, trunc == floor
            float wgt = pos - (float)ifl;
            unsigned u = utab[ifl];        // one ds_read_b32: (tab[i],tab[i+1])
            float lf = __uint_as_float(u << 16);
            float lc = __uint_as_float(u & 0xffff0000u);
            res[j] = fmaf(wgt, lc - lf, lf);
        }
        // A/B vs R14: PLAIN store (via L2 write-back) instead of NT store.
        *reinterpret_cast<f32x4*>(orow + c * 256 + lane * 4) = res;
    }
}

extern "C" void kernel_launch(void* const* d_in, const int* in_sizes, int n_in,
                              void* d_out, int out_size, void* d_ws, size_t ws_size,
                              hipStream_t stream) {
    const float* query   = (const float*)d_in[0];
    const float* attn    = (const float*)d_in[1];
    const float* pos_emb = (const float*)d_in[2];
    const int*   nposp   = (const int*)d_in[3];
    float*       outp    = (float*)d_out;

    const int rows   = in_sizes[1] / KK;   // B*H*Q = 49152
    const int blocks = rows / RPB;         // 3072

    cope_kernel<<<blocks, BLK, 0, stream>>>(query, attn, pos_emb, nposp, outp);
}

// Round 19
// 167.420 us; speedup vs baseline: 1.1297x; 1.1297x over previous
//
#include <hip/hip_runtime.h>
#include <math.h>

// Problem constants (B=2,H=12,Q=2048,K=2048,D=128,NPOS=512)
#define DD    128
#define NPOS  512
#define KK    2048
#define RPB   16        // rows per block = MFMA M dimension
#define BLK   1024      // 16 waves: one wave per row in phase 2

typedef __attribute__((ext_vector_type(8))) short short8_t;  // 8 bf16
typedef __attribute__((ext_vector_type(4))) float f32x4;

union BfPack {
    unsigned u[4];
    short8_t v;
};

__device__ __forceinline__ float sigmoidf_fast(float x) {
    return __builtin_amdgcn_rcpf(1.0f + __expf(-x));
}

__device__ __forceinline__ unsigned pack_bf16(float lo, float hi) {
    return (__float_as_uint(hi) & 0xffff0000u) | (__float_as_uint(lo) >> 16);
}

__global__ __launch_bounds__(BLK, 8)
void cope_kernel(const float* __restrict__ query,     // [R, D]
                 const float* __restrict__ attn,      // [R, K]
                 const float* __restrict__ pos_emb,   // [D, NPOS]
                 const int*   __restrict__ npos_max_p,
                 float* __restrict__ out)              // [R, K]
{
    const int t    = threadIdx.x;
    const int wv   = t >> 6;       // wave id 0..15
    const int lane = t & 63;

    __shared__ float s_tab[RPB][NPOS + 1];   // +1 sentinel col

    const size_t row_base = (size_t)blockIdx.x * RPB;

    // ---------------- Phase 1: table GEMM via bf16 MFMA ----------------
    {
        const int m  = lane & 15;
        const int g  = lane >> 4;
        const int n0 = wv * 32 + m;

        f32x4 acc0 = {0.f, 0.f, 0.f, 0.f};
        f32x4 acc1 = {0.f, 0.f, 0.f, 0.f};

        #pragma unroll
        for (int kk = 0; kk < 4; ++kk) {
            const int k0 = kk * 32 + g * 8;

            const float* qp = query + (row_base + m) * DD + k0;
            f32x4 a0 = *reinterpret_cast<const f32x4*>(qp);
            f32x4 a1 = *reinterpret_cast<const f32x4*>(qp + 4);
            BfPack af;
            af.u[0] = pack_bf16(a0.x, a0.y);
            af.u[1] = pack_bf16(a0.z, a0.w);
            af.u[2] = pack_bf16(a1.x, a1.y);
            af.u[3] = pack_bf16(a1.z, a1.w);

            const float* bp = pos_emb + (size_t)k0 * NPOS + n0;
            float b0[8], b1[8];
            #pragma unroll
            for (int j = 0; j < 8; ++j) {
                b0[j] = bp[(size_t)j * NPOS];
                b1[j] = bp[(size_t)j * NPOS + 16];
            }
            BfPack bf0, bf1;
            #pragma unroll
            for (int j = 0; j < 4; ++j) {
                bf0.u[j] = pack_bf16(b0[2 * j], b0[2 * j + 1]);
                bf1.u[j] = pack_bf16(b1[2 * j], b1[2 * j + 1]);
            }

            acc0 = __builtin_amdgcn_mfma_f32_16x16x32_bf16(af.v, bf0.v, acc0, 0, 0, 0);
            acc1 = __builtin_amdgcn_mfma_f32_16x16x32_bf16(af.v, bf1.v, acc1, 0, 0, 0);
        }

        #pragma unroll
        for (int r = 0; r < 4; ++r) {
            s_tab[g * 4 + r][n0]      = acc0[r];
            s_tab[g * 4 + r][n0 + 16] = acc1[r];
        }
        if (t < RPB) s_tab[t][NPOS] = 0.0f;   // sentinel
    }
    __syncthreads();

    // ---------------- Phase 1.5: repack table to bf16 pairs (in place) -----
    {
        float lo[8], hi[8];
        #pragma unroll
        for (int j = 0; j < 8; ++j) {
            const int e = lane + j * 64;
            lo[j] = s_tab[wv][e];
            hi[j] = s_tab[wv][e + 1];    // e=511 reads the sentinel
        }
        __syncthreads();
        unsigned* urow = reinterpret_cast<unsigned*>(s_tab[wv]);
        #pragma unroll
        for (int j = 0; j < 8; ++j)
            urow[lane + j * 64] = pack_bf16(lo[j], hi[j]);
    }
    __syncthreads();

    // ---------------- Phase 2: per-wave suffix scan + packed gather --------
    const size_t row = row_base + wv;
    const float* arow = attn + row * (size_t)KK;
    float*       orow = out  + row * (size_t)KK;
    const unsigned* utab = reinterpret_cast<const unsigned*>(s_tab[wv]);

    const float clampv = (float)(*npos_max_p - 1);

    float suff[8][4];   // within-lane suffix sums (inclusive)
    float lct[8];       // lane-chunk totals
    float incl[8];      // wave-suffix-inclusive scan of lane totals

    #pragma unroll
    for (int c = 0; c < 8; ++c) {
        f32x4 gv = *reinterpret_cast<const f32x4*>(arow + c * 256 + lane * 4);
        float s0 = sigmoidf_fast(gv.x);
        float s1 = sigmoidf_fast(gv.y);
        float s2 = sigmoidf_fast(gv.z);
        float s3 = sigmoidf_fast(gv.w);
        suff[c][3] = s3;
        suff[c][2] = s2 + suff[c][3];
        suff[c][1] = s1 + suff[c][2];
        suff[c][0] = s0 + suff[c][1];
        lct[c] = suff[c][0];

        // wave-level inclusive suffix scan (64 lanes)
        float v = lct[c];
        #pragma unroll
        for (int off = 1; off < 64; off <<= 1) {
            float u = __shfl_down(v, off);
            if (lane + off < 64) v += u;
        }
        incl[c] = v;
    }

    float Tc[8];
    #pragma unroll
    for (int c = 0; c < 8; ++c) Tc[c] = __shfl(incl[c], 0);
    float offc[8];
    offc[7] = 0.0f;
    #pragma unroll
    for (int c = 6; c >= 0; --c) offc[c] = offc[c + 1] + Tc[c + 1];

    #pragma unroll
    for (int c = 0; c < 8; ++c) {
        float base = offc[c] + (incl[c] - lct[c]);
        f32x4 res;
        #pragma unroll
        for (int j = 0; j < 4; ++j) {
            float pos = fminf(suff[c][j] + base, clampv);
            int   ifl = (int)pos;          // pos >= 0, trunc == floor
            float wgt = pos - (float)ifl;
            unsigned u = utab[ifl];        // one ds_read_b32: (tab[i],tab[i+1])
            float lf = __uint_as_float(u << 16);
            float lc = __uint_as_float(u & 0xffff0000u);
            res[j] = fmaf(wgt, lc - lf, lf);
        }
        __builtin_nontemporal_store(res, reinterpret_cast<f32x4*>(orow + c * 256 + lane * 4));
    }
}

extern "C" void kernel_launch(void* const* d_in, const int* in_sizes, int n_in,
                              void* d_out, int out_size, void* d_ws, size_t ws_size,
                              hipStream_t stream) {
    const float* query   = (const float*)d_in[0];
    const float* attn    = (const float*)d_in[1];
    const float* pos_emb = (const float*)d_in[2];
    const int*   nposp   = (const int*)d_in[3];
    float*       outp    = (float*)d_out;

    const int rows   = in_sizes[1] / KK;   // B*H*Q = 49152
    const int blocks = rows / RPB;         // 3072

    cope_kernel<<<blocks, BLK, 0, stream>>>(query, attn, pos_emb, nposp, outp);
}